// Round 2
// 331.865 us; speedup vs baseline: 1.1955x; 1.1955x over previous
//
#include <hip/hip_runtime.h>

using u16 = unsigned short;
typedef __attribute__((ext_vector_type(8))) short short8;
typedef __attribute__((ext_vector_type(4))) float f32x4;

__device__ __forceinline__ u16 f2bf(float f) {
  unsigned int u = __float_as_uint(f);
  u = (u + 0x7FFFu + ((u >> 16) & 1u)) >> 16;   // RNE, fine for non-NaN
  return (u16)u;
}

// async global->LDS, 16B per lane. LDS dest is wave-uniform base + lane*16.
__device__ __forceinline__ void gload16(const void* g, void* l) {
  __builtin_amdgcn_global_load_lds((const __attribute__((address_space(1))) void*)g,
                                   (__attribute__((address_space(3))) void*)l, 16, 0, 0);
}

#define B_ 4
#define S_ 4096
#define D_ 1024
#define H_ 16
#define HD_ 64
#define M_ (B_*S_)    // 16384
#define N1_ (3*D_)    // 3072
#define NSPLIT_ 4     // kv s-splits (partial buffers, no atomics)

// workspace layout (bytes)
#define OFF_XB    0ull                                  // x bf16 [M][1024]
#define OFF_WQKVT (OFF_XB    + (size_t)M_*D_*2)         // Wqkv^T bf16 [3072][1024]
#define OFF_WOT   (OFF_WQKVT + (size_t)N1_*D_*2)        // Wo^T bf16 [1024][1024]
#define OFF_QBUF  (OFF_WOT   + (size_t)D_*D_*2)         // Q bf16 [M][1024] (elu+1 applied)
#define OFF_KT    (OFF_QBUF  + (size_t)M_*D_*2)         // Kt bf16 [64][64][4096] (elu+1); later attn bf16 [M][1024]
#define OFF_VT    (OFF_KT    + (size_t)M_*D_*2)         // Vt bf16 [64][64][4096]
#define OFF_KV    (OFF_VT    + (size_t)M_*D_*2)         // KV partials fp32 [NSPLIT][bh][64*64]
#define OFF_KSUM  (OFF_KV    + (size_t)NSPLIT_*64*4096*4) // Ksum partials fp32 [NSPLIT][bh][64]
#define WS_NEEDED (OFF_KSUM  + (size_t)NSPLIT_*64*64*4)

// ---------------- merged prep: x->bf16, Wqkv^T, Wo^T (block-range switch) ----------------
__global__ __launch_bounds__(256) void prep_kernel(const float* __restrict__ x, u16* __restrict__ xb,
                                                   const float* __restrict__ Wqkv, u16* __restrict__ wqkvt,
                                                   const float* __restrict__ Wo, u16* __restrict__ wot)
{
  __shared__ float tile[32][33];
  int bid = blockIdx.x, tid = threadIdx.x;
  if (bid < 16384) {
    int i = bid * 256 + tid;               // n4 = M_*D_/4 = 4194304 = 16384*256 exactly
    float4 v = ((const float4*)x)[i];
    uint2 o;
    o.x = (unsigned)f2bf(v.x) | ((unsigned)f2bf(v.y) << 16);
    o.y = (unsigned)f2bf(v.z) | ((unsigned)f2bf(v.w) << 16);
    ((uint2*)xb)[i] = o;
    return;
  }
  const float* in; u16* out; int R, C, cb, rb;
  if (bid < 19456) {
    int t = bid - 16384;  in = Wqkv; out = wqkvt; R = D_; C = N1_;
    cb = t % 96; rb = t / 96;
  } else {
    int t = bid - 19456;  in = Wo; out = wot; R = D_; C = D_;
    cb = t % 32; rb = t / 32;
  }
  int tx = tid & 31, ty = tid >> 5;
  int c0 = cb * 32, r0 = rb * 32;
#pragma unroll
  for (int i = 0; i < 4; i++)
    tile[ty + i*8][tx] = in[(size_t)(r0 + ty + i*8) * C + c0 + tx];
  __syncthreads();
#pragma unroll
  for (int i = 0; i < 4; i++)
    out[(size_t)(c0 + ty + i*8) * R + r0 + tx] = f2bf(tile[tx][ty + i*8]);
}

// ---------------- main GEMM: 256x256 tile, BK=32, ring-4 LDS pipeline ----------------
// C[M,N] = A[M,K](bf16) * Bt[N,K](bf16)^T.
// 512 threads = 8 waves (2 M x 4 N); wave tile 128x64; acc 8x4 frags.
// Pipeline: per K-step t, issue global_load_lds for step t+3 (slot (t+3)&3, last read
// at t-1, so the barrier ending t-1 legalizes the overwrite); compute step t; then
// counted s_waitcnt (steps t+2,t+3 stay in flight; t+1 guaranteed landed) + raw
// s_barrier. Loads never drain in the main loop (T4). DRAIN TAIL (last 4 steps):
// wait counts shrink 8 -> 4 -> 0 so each next step's loads are guaranteed landed
// (round-0 bug: constant vmcnt(8) became a no-op once staging stopped -> race).
// LDS layout per 16KB panel: paired rows [128 phys rows][8 chunks of 16B];
// logical (r,kchunk) stored at phys chunk pch = (((r&1)<<2)|kchunk) ^ ((r>>1)&7).
// XOR is an involution: applied to the global fetch address on staging, and to the
// ds_read address on the fragment read -> conflict-free column-slice reads.
// mode 0: fp32 store to Cf.  mode 1: qkv epilogue (Q elu+1 / Kt,Vt transposed pack).
__global__ __launch_bounds__(512, 2) void gemm256(
    const u16* __restrict__ A, const u16* __restrict__ Bt,
    float* __restrict__ Cf, u16* __restrict__ qout,
    u16* __restrict__ Kt, u16* __restrict__ Vt,
    int M, int N, int K, int mode)
{
  __shared__ __align__(16) char smem[131072];   // [4 slots][A 16KB] + [4 slots][B 16KB]
  int tid = threadIdx.x;
  int w = tid >> 6, lane = tid & 63;
  int quad = lane >> 4, l16 = lane & 15;
  int wm = w >> 2, wn = w & 3;

  // XCD-aware bijective swizzle (both call sites have nwg % 8 == 0)
  int nwg = gridDim.x * gridDim.y;
  int flat = blockIdx.y * gridDim.x + blockIdx.x;
  int wg = (flat & 7) * (nwg >> 3) + (flat >> 3);
  int bx = wg % gridDim.x, by = wg / gridDim.x;
  int bm = by * 256, bn = bx * 256;

  // ---- staging setup: 4 x gload16 per thread per K-step ----
  // thread covers LDS bytes lane*16 within its wave's 1KB strip; invert the swizzle
  // into the global source address (rule #21: linear dest + inverse-swz source).
  int prl = lane >> 3;                          // phys row-in-strip 0..7
  int c4  = (lane & 7) ^ prl;                   // logical chunk 0..7
  int r0  = ((w << 3) + prl) * 2 + (c4 >> 2);   // logical row 0..127
  int koff = (c4 & 3) * 8;                      // logical k element offset
  const u16* gA0 = A  + (size_t)(bm + r0) * K + koff;
  const u16* gB0 = Bt + (size_t)(bn + r0) * K + koff;
  size_t rowskip = (size_t)128 * K;             // logical rows +128 (phys rows +64)
  char* smemc = smem;
  int ldsAw = w * 1024;                         // wave-uniform LDS bases
  int ldsBw = 65536 + w * 1024;

  // ---- fragment read bases (constant per thread; slot/mi/nj become immediates) ----
  // A-frag mi: logical row wm*128 + mi*16 + l16, kchunk = quad
  //   pr = wm*64 + mi*8 + (l16>>1); pr&7 = (l16>>1)&7 (mi*8, wm*64 vanish mod 8)
  int ph = (((l16 & 1) << 2) | quad) ^ ((l16 >> 1) & 7);
  int baseA = wm * 8192 + (l16 >> 1) * 128 + ph * 16;
  int baseB = 65536 + wn * 4096 + (l16 >> 1) * 128 + ph * 16;

  f32x4 acc[8][4];
#pragma unroll
  for (int i = 0; i < 8; i++)
#pragma unroll
    for (int j = 0; j < 4; j++) acc[i][j] = (f32x4)0.0f;

  int nt = K >> 5;   // K=1024 -> 32 steps (requires K%128==0, nt>=8)

#define STG(tt, slot) {                                                   \
    const u16* a0_ = gA0 + (tt) * 32;                                     \
    const u16* b0_ = gB0 + (tt) * 32;                                     \
    gload16(a0_,           smemc + (slot)*16384 + ldsAw);                 \
    gload16(a0_ + rowskip, smemc + (slot)*16384 + 8192 + ldsAw);          \
    gload16(b0_,           smemc + (slot)*16384 + ldsBw);                 \
    gload16(b0_ + rowskip, smemc + (slot)*16384 + 8192 + ldsBw);          \
  }

#define COMPUTE(slot) {                                                              \
    const char* sb = smemc + (slot) * 16384;                                         \
    short8 bfr[4], af[8];                                                            \
    _Pragma("unroll")                                                                \
    for (int nj = 0; nj < 4; nj++) bfr[nj] = *(const short8*)(sb + baseB + nj*1024); \
    _Pragma("unroll")                                                                \
    for (int mi = 0; mi < 8; mi++) af[mi] = *(const short8*)(sb + baseA + mi*1024);  \
    __builtin_amdgcn_s_setprio(1);                                                   \
    _Pragma("unroll")                                                                \
    for (int mi = 0; mi < 8; mi++)                                                   \
      _Pragma("unroll")                                                              \
      for (int nj = 0; nj < 4; nj++)                                                 \
        acc[mi][nj] = __builtin_amdgcn_mfma_f32_16x16x32_bf16(af[mi], bfr[nj],       \
                                                              acc[mi][nj], 0, 0, 0); \
    __builtin_amdgcn_s_setprio(0);                                                   \
  }

#define WAITBAR(n) {                                                      \
    asm volatile("s_waitcnt vmcnt(" #n ")" ::: "memory");                 \
    __builtin_amdgcn_s_barrier();                                         \
    asm volatile("" ::: "memory");                                        \
  }

  // prologue: 3 steps in flight; wait for step 0 only (newest 8 loads may be pending)
  STG(0, 0); STG(1, 1); STG(2, 2);
  WAITBAR(8)

  // main loop: steps 0 .. nt-5; STG(t+3) always valid (t+3 <= nt-2)
  for (int tb = 0; tb < nt - 4; tb += 4) {
#pragma unroll
    for (int i = 0; i < 4; ++i) {
      int t = tb + i;
      STG(t + 3, ((i + 3) & 3));        // slot (t-1)&3: freed by preceding barrier
      COMPUTE(i)
      WAITBAR(8)                        // t+2, t+3 stay in flight; t+1 landed
    }
  }

  // drain tail: steps nt-4 .. nt-1 in slots 0..3, wait counts shrink 8/4/0
  STG(nt - 1, 3);                       // slot 3 freed by last main-loop barrier
  COMPUTE(0)
  WAITBAR(8)                            // nt-3,nt-2,nt-1 outstanding(12) -> nt-3 landed
  COMPUTE(1)
  WAITBAR(4)                            // nt-2,nt-1 outstanding(8) -> nt-2 landed
  COMPUTE(2)
  WAITBAR(0)                            // nt-1 landed
  COMPUTE(3)

#undef STG
#undef COMPUTE
#undef WAITBAR

  // C/D layout: col = lane&15 (+nj*16), row = quad*4 + reg (verified m89/m91)
  int colbase = bn + wn * 64;
  if (mode == 0) {
#pragma unroll
    for (int mi = 0; mi < 8; mi++) {
      int row0 = bm + wm * 128 + mi * 16 + quad * 4;
#pragma unroll
      for (int nj = 0; nj < 4; nj++) {
        int col = colbase + nj * 16 + l16;
#pragma unroll
        for (int r = 0; r < 4; r++)
          Cf[(size_t)(row0 + r) * N + col] = acc[mi][nj][r];
      }
    }
  } else {
    int cls = colbase >> 10;   // 0=Q, 1=K, 2=V (wave-uniform: 64 | 1024)
    if (cls == 0) {
#pragma unroll
      for (int mi = 0; mi < 8; mi++) {
        int row0 = bm + wm * 128 + mi * 16 + quad * 4;
#pragma unroll
        for (int nj = 0; nj < 4; nj++) {
          int col = colbase + nj * 16 + l16;
#pragma unroll
          for (int r = 0; r < 4; r++) {
            float v = acc[mi][nj][r];
            v = (v > 0.0f) ? (v + 1.0f) : __expf(v);   // elu+1
            qout[(size_t)(row0 + r) * D_ + col] = f2bf(v);
          }
        }
      }
    } else {
      int b = bm >> 12;                       // 4096 rows per batch; bm % 4096 block-uniform
      int h = (colbase & 1023) >> 6;          // head of this wave's 64-col subtile
      u16* dst = (cls == 1 ? Kt : Vt) + (size_t)((b * 16 + h) * 64) * 4096;
      int sb0 = (bm & 4095) + wm * 128;
      bool doElu = (cls == 1);
#pragma unroll
      for (int mi = 0; mi < 8; mi++) {
        int s = sb0 + mi * 16 + quad * 4;
#pragma unroll
        for (int nj = 0; nj < 4; nj++) {
          int d = nj * 16 + l16;
          float v0 = acc[mi][nj][0], v1 = acc[mi][nj][1], v2 = acc[mi][nj][2], v3 = acc[mi][nj][3];
          if (doElu) {
            v0 = (v0 > 0.0f) ? (v0 + 1.0f) : __expf(v0);
            v1 = (v1 > 0.0f) ? (v1 + 1.0f) : __expf(v1);
            v2 = (v2 > 0.0f) ? (v2 + 1.0f) : __expf(v2);
            v3 = (v3 > 0.0f) ? (v3 + 1.0f) : __expf(v3);
          }
          uint2 o;
          o.x = (unsigned)f2bf(v0) | ((unsigned)f2bf(v1) << 16);
          o.y = (unsigned)f2bf(v2) | ((unsigned)f2bf(v3) << 16);
          *(uint2*)(dst + (size_t)d * 4096 + s) = o;   // 4 consecutive s, one d
        }
      }
    }
  }
}

// ---------------- KV partial[p][bh] = sum_{s in split p} K[s,d]V[s,v]; NO global atomics ----------------
__global__ __launch_bounds__(256) void kv_kernel(const u16* __restrict__ Kt,
                                                 const u16* __restrict__ Vt,
                                                 float* __restrict__ KVp,
                                                 float* __restrict__ Ksp)
{
  __shared__ float red[4096];
  __shared__ float redS[64];
  int tid = threadIdx.x;
  int bh = blockIdx.x;
  int ssplit = blockIdx.y;
  int wave = tid >> 6, lane = tid & 63, quad = lane >> 4, l16 = lane & 15;
  int sbase = ssplit * (S_ / NSPLIT_) + wave * (S_ / NSPLIT_ / 4);
  const u16* Kb = Kt + (size_t)bh * 64 * 4096;
  const u16* Vb = Vt + (size_t)bh * 64 * 4096;
  short8 ones;
#pragma unroll
  for (int e = 0; e < 8; ++e) ones[e] = (short)0x3F80;   // bf16 1.0

  for (int i = tid; i < 4096; i += 256) red[i] = 0.0f;
  if (tid < 64) redS[tid] = 0.0f;

  f32x4 acc[4][4], accs[4];
#pragma unroll
  for (int i = 0; i < 4; i++) {
    accs[i] = (f32x4)0.0f;
#pragma unroll
    for (int j = 0; j < 4; j++) acc[i][j] = (f32x4)0.0f;
  }

  for (int kk = 0; kk < S_ / NSPLIT_ / 4 / 32; ++kk) {   // 8 iters of 32 s
    int s = sbase + kk * 32 + quad * 8;
    short8 af[4], bfr[4];
#pragma unroll
    for (int i = 0; i < 4; i++) {
      af[i]  = *(const short8*)(Kb + (size_t)(i*16 + l16) * 4096 + s);
      bfr[i] = *(const short8*)(Vb + (size_t)(i*16 + l16) * 4096 + s);
    }
#pragma unroll
    for (int i = 0; i < 4; i++) {
#pragma unroll
      for (int j = 0; j < 4; j++)
        acc[i][j] = __builtin_amdgcn_mfma_f32_16x16x32_bf16(af[i], bfr[j], acc[i][j], 0, 0, 0);
      accs[i] = __builtin_amdgcn_mfma_f32_16x16x32_bf16(af[i], ones, accs[i], 0, 0, 0);
    }
  }
  __syncthreads();   // zeroing complete
#pragma unroll
  for (int i = 0; i < 4; i++) {
    int d0 = i*16 + quad*4;
#pragma unroll
    for (int j = 0; j < 4; j++)
#pragma unroll
      for (int r = 0; r < 4; r++)
        atomicAdd(&red[(d0 + r) * 64 + j*16 + l16], acc[i][j][r]);   // LDS ds_add_f32
    if (l16 == 0)
#pragma unroll
      for (int r = 0; r < 4; r++)
        atomicAdd(&redS[d0 + r], accs[i][r]);
  }
  __syncthreads();
  float* dst = KVp + ((size_t)ssplit * 64 + bh) * 4096;
  for (int i = tid; i < 4096; i += 256) dst[i] = red[i];
  if (tid < 64) Ksp[((size_t)ssplit * 64 + bh) * 64 + tid] = redS[tid];
}

// ---------------- attn[s][h*64+v] = (Q[s,:]@KV) / (Q[s,:]@Ksum + eps), bf16 out ----------------
__global__ __launch_bounds__(256) void attn_kernel(const u16* __restrict__ qbuf,
                                                   const float* __restrict__ KVp,
                                                   const float* __restrict__ Ksp,
                                                   u16* __restrict__ attn)
{
  __shared__ u16 KVt[64 * 72];   // [v][d], stride 72
  int tid = threadIdx.x;
  int bh = blockIdx.y;
  int b = bh >> 4, h = bh & 15;
  int s0 = blockIdx.x * 128;
  const float* kvsrc = KVp + (size_t)bh * 4096;
  for (int i = tid; i < 4096; i += 256) {
    float s = kvsrc[i] + kvsrc[i + 64*4096] + kvsrc[i + 2*64*4096] + kvsrc[i + 3*64*4096];
    int d = i >> 6, v = i & 63;
    KVt[v * 72 + d] = f2bf(s);
  }
  __syncthreads();
  int wave = tid >> 6, lane = tid & 63, quad = lane >> 4, l16 = lane & 15;

  const float* kssrc = Ksp + (size_t)bh * 64;
  short8 bks[2];
#pragma unroll
  for (int ks = 0; ks < 2; ++ks)
#pragma unroll
    for (int jj = 0; jj < 8; ++jj) {
      int d = ks*32 + quad*8 + jj;
      float s = kssrc[d] + kssrc[d + 64*64] + kssrc[d + 2*64*64] + kssrc[d + 3*64*64];
      bks[ks][jj] = (short)f2bf(s);
    }

  f32x4 acc[2][4], accn[2];
#pragma unroll
  for (int i = 0; i < 2; i++) {
    accn[i] = (f32x4)0.0f;
#pragma unroll
    for (int j = 0; j < 4; j++) acc[i][j] = (f32x4)0.0f;
  }

#pragma unroll
  for (int ks = 0; ks < 2; ++ks) {
    short8 bfr[4];
#pragma unroll
    for (int j = 0; j < 4; j++)
      bfr[j] = *(const short8*)(&KVt[(j*16 + l16) * 72 + ks*32 + quad*8]);
#pragma unroll
    for (int i = 0; i < 2; i++) {
      int row = s0 + wave * 32 + i * 16 + l16;
      short8 afr = *(const short8*)(qbuf + (size_t)(b * S_ + row) * D_ + h*HD_ + ks*32 + quad*8);
#pragma unroll
      for (int j = 0; j < 4; j++)
        acc[i][j] = __builtin_amdgcn_mfma_f32_16x16x32_bf16(afr, bfr[j], acc[i][j], 0, 0, 0);
      accn[i] = __builtin_amdgcn_mfma_f32_16x16x32_bf16(afr, bks[ks], accn[i], 0, 0, 0);
    }
  }
#pragma unroll
  for (int i = 0; i < 2; i++) {
    int rb = wave * 32 + i * 16 + quad * 4;
#pragma unroll
    for (int j = 0; j < 4; j++) {
      int col = h * HD_ + j * 16 + l16;
#pragma unroll
      for (int r = 0; r < 4; r++) {
        float o = acc[i][j][r] / (accn[i][r] + 1e-6f);
        attn[(size_t)(b * S_ + s0 + rb + r) * D_ + col] = f2bf(o);
      }
    }
  }
}

extern "C" void kernel_launch(void* const* d_in, const int* in_sizes, int n_in,
                              void* d_out, int out_size, void* d_ws, size_t ws_size,
                              hipStream_t stream) {
  const float* x    = (const float*)d_in[0];
  const float* Wqkv = (const float*)d_in[1];
  const float* Wo   = (const float*)d_in[2];
  float* out = (float*)d_out;
  char* ws = (char*)d_ws;
  if (ws_size < WS_NEEDED) return;  // visible failure, no corruption

  u16*   xb    = (u16*)  (ws + OFF_XB);
  u16*   wqkvt = (u16*)  (ws + OFF_WQKVT);
  u16*   wot   = (u16*)  (ws + OFF_WOT);
  u16*   qbuf  = (u16*)  (ws + OFF_QBUF);
  u16*   kt    = (u16*)  (ws + OFF_KT);
  u16*   vt    = (u16*)  (ws + OFF_VT);
  float* kvp   = (float*)(ws + OFF_KV);
  float* ksp   = (float*)(ws + OFF_KSUM);
  u16*   attnb = (u16*)  (ws + OFF_KT);    // aliases Kt: dead after kv_kernel

  prep_kernel<<<20480, 256, 0, stream>>>(x, xb, Wqkv, wqkvt, Wo, wot);
  // qkv = x @ Wqkv; epilogue splits Q (elu, [M][1024]) / Kt,Vt (transposed [bh][d][S])
  gemm256<<<dim3(N1_/256, M_/256), 512, 0, stream>>>(xb, wqkvt, nullptr, qbuf, kt, vt,
                                                     M_, N1_, D_, 1);
  kv_kernel<<<dim3(64, NSPLIT_), 256, 0, stream>>>(kt, vt, kvp, ksp);
  attn_kernel<<<dim3(32, 64), 256, 0, stream>>>(qbuf, kvp, ksp, attnb);
  // final = attn @ Wo, fp32 out
  gemm256<<<dim3(D_/256, M_/256), 512, 0, stream>>>(attnb, wot, out, nullptr, nullptr, nullptr,
                                                    M_, D_, D_, 0);
}

// Round 3
// 329.436 us; speedup vs baseline: 1.2043x; 1.0074x over previous
//
#include <hip/hip_runtime.h>

using u16 = unsigned short;
typedef __attribute__((ext_vector_type(8))) short short8;
typedef __attribute__((ext_vector_type(4))) float f32x4;

__device__ __forceinline__ u16 f2bf(float f) {
  unsigned int u = __float_as_uint(f);
  u = (u + 0x7FFFu + ((u >> 16) & 1u)) >> 16;   // RNE, fine for non-NaN
  return (u16)u;
}

// async global->LDS, 16B per lane. LDS dest is wave-uniform base + lane*16.
__device__ __forceinline__ void gload16(const void* g, void* l) {
  __builtin_amdgcn_global_load_lds((const __attribute__((address_space(1))) void*)g,
                                   (__attribute__((address_space(3))) void*)l, 16, 0, 0);
}

#define B_ 4
#define S_ 4096
#define D_ 1024
#define H_ 16
#define HD_ 64
#define M_ (B_*S_)    // 16384
#define N1_ (3*D_)    // 3072
#define NSPLIT_ 4     // kv s-splits (partial buffers, no atomics)

// workspace layout (bytes)
#define OFF_XB    0ull                                  // x bf16 [M][1024]
#define OFF_WQKVT (OFF_XB    + (size_t)M_*D_*2)         // Wqkv^T bf16 [3072][1024]
#define OFF_WOT   (OFF_WQKVT + (size_t)N1_*D_*2)        // Wo^T bf16 [1024][1024]
#define OFF_QBUF  (OFF_WOT   + (size_t)D_*D_*2)         // Q bf16 [M][1024] (elu+1 applied)
#define OFF_KT    (OFF_QBUF  + (size_t)M_*D_*2)         // Kt bf16 [64][64][4096] (elu+1); later attn bf16 [M][1024]
#define OFF_VT    (OFF_KT    + (size_t)M_*D_*2)         // Vt bf16 [64][64][4096]
#define OFF_KV    (OFF_VT    + (size_t)M_*D_*2)         // KV partials fp32 [NSPLIT][bh][64*64]
#define OFF_KSUM  (OFF_KV    + (size_t)NSPLIT_*64*4096*4) // Ksum partials fp32 [NSPLIT][bh][64]
#define WS_NEEDED (OFF_KSUM  + (size_t)NSPLIT_*64*64*4)

// ---------------- merged prep: x->bf16, Wqkv^T, Wo^T (block-range switch) ----------------
__global__ __launch_bounds__(256) void prep_kernel(const float* __restrict__ x, u16* __restrict__ xb,
                                                   const float* __restrict__ Wqkv, u16* __restrict__ wqkvt,
                                                   const float* __restrict__ Wo, u16* __restrict__ wot)
{
  __shared__ float tile[32][33];
  int bid = blockIdx.x, tid = threadIdx.x;
  if (bid < 16384) {
    int i = bid * 256 + tid;               // n4 = M_*D_/4 = 4194304 = 16384*256 exactly
    float4 v = ((const float4*)x)[i];
    uint2 o;
    o.x = (unsigned)f2bf(v.x) | ((unsigned)f2bf(v.y) << 16);
    o.y = (unsigned)f2bf(v.z) | ((unsigned)f2bf(v.w) << 16);
    ((uint2*)xb)[i] = o;
    return;
  }
  const float* in; u16* out; int R, C, cb, rb;
  if (bid < 19456) {
    int t = bid - 16384;  in = Wqkv; out = wqkvt; R = D_; C = N1_;
    cb = t % 96; rb = t / 96;
  } else {
    int t = bid - 19456;  in = Wo; out = wot; R = D_; C = D_;
    cb = t % 32; rb = t / 32;
  }
  int tx = tid & 31, ty = tid >> 5;
  int c0 = cb * 32, r0 = rb * 32;
#pragma unroll
  for (int i = 0; i < 4; i++)
    tile[ty + i*8][tx] = in[(size_t)(r0 + ty + i*8) * C + c0 + tx];
  __syncthreads();
#pragma unroll
  for (int i = 0; i < 4; i++)
    out[(size_t)(c0 + ty + i*8) * R + r0 + tx] = f2bf(tile[tx][ty + i*8]);
}

// ---------------- main GEMM: 256x256 tile, BK=32, ring-4 LDS, 2-phase K-step ----------------
// C[M,N] = A[M,K](bf16) * Bt[N,K](bf16)^T.
// 512 threads = 8 waves (2 M x 4 N); wave tile 128x64; acc 8x4 frags.
// Ring-4 pipeline (unchanged ledger): per K-step t, stage step t+3 into slot (t+3)&3
// (freed by the final barrier of step t-1); end-of-step counted s_waitcnt vmcnt(8)
// guarantees tile t+1 landed while t+2,t+3 stay in flight; drain tail shrinks 8/4/0.
// NEW (m201 phase structure): each K-step is TWO phases, each
//   {stage-half gloads; ds_reads; s_barrier; lgkmcnt(0)+sched_barrier; setprio(1);
//    16 MFMA; setprio(0); s_barrier}
// Phase A: A-half stage, 8 reads (bfr0-3 + af0-3), MFMA mi0-3.
// Phase B: B-half stage, 4 reads (af4-7; bfr kept in reg), MFMA mi4-7, vmcnt(8).
// 4 barriers per K-32 step = m201's density (1 per 8 K-elems); pure-MFMA clusters
// make setprio effective (T5 requires the phase role-split, m218b).
// LDS layout per 16KB panel: paired rows [128 phys rows][8 chunks of 16B];
// logical (r,kchunk) stored at phys chunk pch = (((r&1)<<2)|kchunk) ^ ((r>>1)&7).
// XOR involution applied to the global fetch address on staging and to the ds_read
// address on the fragment read -> conflict-free column-slice reads (verified: 0 conflicts).
// mode 0: fp32 store to Cf.  mode 1: qkv epilogue (Q elu+1 / Kt,Vt transposed pack).
__global__ __launch_bounds__(512, 2) void gemm256(
    const u16* __restrict__ A, const u16* __restrict__ Bt,
    float* __restrict__ Cf, u16* __restrict__ qout,
    u16* __restrict__ Kt, u16* __restrict__ Vt,
    int M, int N, int K, int mode)
{
  __shared__ __align__(16) char smem[131072];   // [4 slots][A 16KB] + [4 slots][B 16KB]
  int tid = threadIdx.x;
  int w = tid >> 6, lane = tid & 63;
  int quad = lane >> 4, l16 = lane & 15;
  int wm = w >> 2, wn = w & 3;

  // XCD-aware bijective swizzle (both call sites have nwg % 8 == 0)
  int nwg = gridDim.x * gridDim.y;
  int flat = blockIdx.y * gridDim.x + blockIdx.x;
  int wg = (flat & 7) * (nwg >> 3) + (flat >> 3);
  int bx = wg % gridDim.x, by = wg / gridDim.x;
  int bm = by * 256, bn = bx * 256;

  // ---- staging setup: 4 x gload16 per thread per K-step ----
  // thread covers LDS bytes lane*16 within its wave's 1KB strip; invert the swizzle
  // into the global source address (rule #21: linear dest + inverse-swz source).
  int prl = lane >> 3;                          // phys row-in-strip 0..7
  int c4  = (lane & 7) ^ prl;                   // logical chunk 0..7
  int r0  = ((w << 3) + prl) * 2 + (c4 >> 2);   // logical row 0..127
  int koff = (c4 & 3) * 8;                      // logical k element offset
  const u16* gA0 = A  + (size_t)(bm + r0) * K + koff;
  const u16* gB0 = Bt + (size_t)(bn + r0) * K + koff;
  size_t rowskip = (size_t)128 * K;             // logical rows +128 (phys rows +64)
  char* smemc = smem;
  int ldsAw = w * 1024;                         // wave-uniform LDS bases
  int ldsBw = 65536 + w * 1024;

  // ---- fragment read bases (constant per thread; slot/mi/nj become immediates) ----
  // A-frag mi: logical row wm*128 + mi*16 + l16, kchunk = quad
  //   pr = wm*64 + mi*8 + (l16>>1); pr&7 = (l16>>1)&7 (mi*8, wm*64 vanish mod 8)
  int ph = (((l16 & 1) << 2) | quad) ^ ((l16 >> 1) & 7);
  int baseA = wm * 8192 + (l16 >> 1) * 128 + ph * 16;
  int baseB = 65536 + wn * 4096 + (l16 >> 1) * 128 + ph * 16;

  f32x4 acc[8][4];
#pragma unroll
  for (int i = 0; i < 8; i++)
#pragma unroll
    for (int j = 0; j < 4; j++) acc[i][j] = (f32x4)0.0f;

  int nt = K >> 5;   // K=1024 -> 32 steps (requires K%128==0, nt>=8)

#define STGA(tt, slot) {                                                  \
    const u16* a0_ = gA0 + (tt) * 32;                                     \
    gload16(a0_,           smemc + (slot)*16384 + ldsAw);                 \
    gload16(a0_ + rowskip, smemc + (slot)*16384 + 8192 + ldsAw);          \
  }
#define STGB(tt, slot) {                                                  \
    const u16* b0_ = gB0 + (tt) * 32;                                     \
    gload16(b0_,           smemc + (slot)*16384 + ldsBw);                 \
    gload16(b0_ + rowskip, smemc + (slot)*16384 + 8192 + ldsBw);          \
  }
#define VM(n) asm volatile("s_waitcnt vmcnt(" #n ")" ::: "memory");

  // One K-step = two m201-style phases. SA/SB are the half-stage statements
  // (possibly empty in the drain tail); ENDW is the counted vmcnt (or empty).
#define STEP(slot, SA, SB, ENDW) {                                                    \
    const char* sb = smemc + (slot) * 16384;                                          \
    short8 bfr[4], af[4];                                                             \
    SA                                                                                \
    _Pragma("unroll")                                                                 \
    for (int nj = 0; nj < 4; nj++) bfr[nj] = *(const short8*)(sb + baseB + nj*1024);  \
    _Pragma("unroll")                                                                 \
    for (int mi = 0; mi < 4; mi++) af[mi] = *(const short8*)(sb + baseA + mi*1024);   \
    __builtin_amdgcn_s_barrier();                                                     \
    asm volatile("s_waitcnt lgkmcnt(0)" ::: "memory");                                \
    __builtin_amdgcn_sched_barrier(0);                                                \
    __builtin_amdgcn_s_setprio(1);                                                    \
    _Pragma("unroll")                                                                 \
    for (int mi = 0; mi < 4; mi++)                                                    \
      _Pragma("unroll")                                                               \
      for (int nj = 0; nj < 4; nj++)                                                  \
        acc[mi][nj] = __builtin_amdgcn_mfma_f32_16x16x32_bf16(af[mi], bfr[nj],        \
                                                              acc[mi][nj], 0, 0, 0);  \
    __builtin_amdgcn_s_setprio(0);                                                    \
    __builtin_amdgcn_s_barrier();                                                     \
    SB                                                                                \
    _Pragma("unroll")                                                                 \
    for (int mi = 0; mi < 4; mi++) af[mi] = *(const short8*)(sb + baseA + (mi+4)*1024);\
    __builtin_amdgcn_s_barrier();                                                     \
    asm volatile("s_waitcnt lgkmcnt(0)" ::: "memory");                                \
    __builtin_amdgcn_sched_barrier(0);                                                \
    __builtin_amdgcn_s_setprio(1);                                                    \
    _Pragma("unroll")                                                                 \
    for (int mi = 0; mi < 4; mi++)                                                    \
      _Pragma("unroll")                                                               \
      for (int nj = 0; nj < 4; nj++)                                                  \
        acc[mi+4][nj] = __builtin_amdgcn_mfma_f32_16x16x32_bf16(af[mi], bfr[nj],      \
                                                                acc[mi+4][nj], 0, 0, 0);\
    __builtin_amdgcn_s_setprio(0);                                                    \
    ENDW                                                                              \
    __builtin_amdgcn_s_barrier();                                                     \
    asm volatile("" ::: "memory");                                                    \
  }

  // prologue: 3 tiles in flight; wait tile 0 (oldest 4 of 12)
  STGA(0, 0) STGB(0, 0)
  STGA(1, 1) STGB(1, 1)
  STGA(2, 2) STGB(2, 2)
  VM(8)
  __builtin_amdgcn_s_barrier();
  asm volatile("" ::: "memory");

  // main loop: steps 0 .. nt-5; STG(t+3) always valid (t+3 <= nt-2).
  // End-of-step vmcnt(8): outstanding t+1,t+2,t+3 (12) -> tile t+1 landed.
  for (int tb = 0; tb < nt - 4; tb += 4) {
#pragma unroll
    for (int i = 0; i < 4; ++i) {
      int t = tb + i;
      STEP(i, STGA(t + 3, ((i + 3) & 3)), STGB(t + 3, ((i + 3) & 3)), VM(8))
    }
  }

  // drain tail: steps nt-4 .. nt-1 in slots 0..3; wait counts shrink 8/4/0/none
  STEP(0, STGA(nt - 1, 3), STGB(nt - 1, 3), VM(8))   // nt-3,nt-2,nt-1 out(12) -> nt-3 landed
  STEP(1, , , VM(4))                                 // nt-2,nt-1 out(8)  -> nt-2 landed
  STEP(2, , , VM(0))                                 // nt-1 landed
  STEP(3, , , )

#undef STEP
#undef STGA
#undef STGB
#undef VM

  // C/D layout: col = lane&15 (+nj*16), row = quad*4 + reg (verified m89/m91)
  int colbase = bn + wn * 64;
  if (mode == 0) {
#pragma unroll
    for (int mi = 0; mi < 8; mi++) {
      int row0 = bm + wm * 128 + mi * 16 + quad * 4;
#pragma unroll
      for (int nj = 0; nj < 4; nj++) {
        int col = colbase + nj * 16 + l16;
#pragma unroll
        for (int r = 0; r < 4; r++)
          Cf[(size_t)(row0 + r) * N + col] = acc[mi][nj][r];
      }
    }
  } else {
    int cls = colbase >> 10;   // 0=Q, 1=K, 2=V (wave-uniform: 64 | 1024)
    if (cls == 0) {
#pragma unroll
      for (int mi = 0; mi < 8; mi++) {
        int row0 = bm + wm * 128 + mi * 16 + quad * 4;
#pragma unroll
        for (int nj = 0; nj < 4; nj++) {
          int col = colbase + nj * 16 + l16;
#pragma unroll
          for (int r = 0; r < 4; r++) {
            float v = acc[mi][nj][r];
            v = (v > 0.0f) ? (v + 1.0f) : __expf(v);   // elu+1
            qout[(size_t)(row0 + r) * D_ + col] = f2bf(v);
          }
        }
      }
    } else {
      int b = bm >> 12;                       // 4096 rows per batch; bm % 4096 block-uniform
      int h = (colbase & 1023) >> 6;          // head of this wave's 64-col subtile
      u16* dst = (cls == 1 ? Kt : Vt) + (size_t)((b * 16 + h) * 64) * 4096;
      int sb0 = (bm & 4095) + wm * 128;
      bool doElu = (cls == 1);
#pragma unroll
      for (int mi = 0; mi < 8; mi++) {
        int s = sb0 + mi * 16 + quad * 4;
#pragma unroll
        for (int nj = 0; nj < 4; nj++) {
          int d = nj * 16 + l16;
          float v0 = acc[mi][nj][0], v1 = acc[mi][nj][1], v2 = acc[mi][nj][2], v3 = acc[mi][nj][3];
          if (doElu) {
            v0 = (v0 > 0.0f) ? (v0 + 1.0f) : __expf(v0);
            v1 = (v1 > 0.0f) ? (v1 + 1.0f) : __expf(v1);
            v2 = (v2 > 0.0f) ? (v2 + 1.0f) : __expf(v2);
            v3 = (v3 > 0.0f) ? (v3 + 1.0f) : __expf(v3);
          }
          uint2 o;
          o.x = (unsigned)f2bf(v0) | ((unsigned)f2bf(v1) << 16);
          o.y = (unsigned)f2bf(v2) | ((unsigned)f2bf(v3) << 16);
          *(uint2*)(dst + (size_t)d * 4096 + s) = o;   // 4 consecutive s, one d
        }
      }
    }
  }
}

// ---------------- KV partial[p][bh] = sum_{s in split p} K[s,d]V[s,v]; NO global atomics ----------------
__global__ __launch_bounds__(256) void kv_kernel(const u16* __restrict__ Kt,
                                                 const u16* __restrict__ Vt,
                                                 float* __restrict__ KVp,
                                                 float* __restrict__ Ksp)
{
  __shared__ float red[4096];
  __shared__ float redS[64];
  int tid = threadIdx.x;
  int bh = blockIdx.x;
  int ssplit = blockIdx.y;
  int wave = tid >> 6, lane = tid & 63, quad = lane >> 4, l16 = lane & 15;
  int sbase = ssplit * (S_ / NSPLIT_) + wave * (S_ / NSPLIT_ / 4);
  const u16* Kb = Kt + (size_t)bh * 64 * 4096;
  const u16* Vb = Vt + (size_t)bh * 64 * 4096;
  short8 ones;
#pragma unroll
  for (int e = 0; e < 8; ++e) ones[e] = (short)0x3F80;   // bf16 1.0

  for (int i = tid; i < 4096; i += 256) red[i] = 0.0f;
  if (tid < 64) redS[tid] = 0.0f;

  f32x4 acc[4][4], accs[4];
#pragma unroll
  for (int i = 0; i < 4; i++) {
    accs[i] = (f32x4)0.0f;
#pragma unroll
    for (int j = 0; j < 4; j++) acc[i][j] = (f32x4)0.0f;
  }

  for (int kk = 0; kk < S_ / NSPLIT_ / 4 / 32; ++kk) {   // 8 iters of 32 s
    int s = sbase + kk * 32 + quad * 8;
    short8 af[4], bfr[4];
#pragma unroll
    for (int i = 0; i < 4; i++) {
      af[i]  = *(const short8*)(Kb + (size_t)(i*16 + l16) * 4096 + s);
      bfr[i] = *(const short8*)(Vb + (size_t)(i*16 + l16) * 4096 + s);
    }
#pragma unroll
    for (int i = 0; i < 4; i++) {
#pragma unroll
      for (int j = 0; j < 4; j++)
        acc[i][j] = __builtin_amdgcn_mfma_f32_16x16x32_bf16(af[i], bfr[j], acc[i][j], 0, 0, 0);
      accs[i] = __builtin_amdgcn_mfma_f32_16x16x32_bf16(af[i], ones, accs[i], 0, 0, 0);
    }
  }
  __syncthreads();   // zeroing complete
#pragma unroll
  for (int i = 0; i < 4; i++) {
    int d0 = i*16 + quad*4;
#pragma unroll
    for (int j = 0; j < 4; j++)
#pragma unroll
      for (int r = 0; r < 4; r++)
        atomicAdd(&red[(d0 + r) * 64 + j*16 + l16], acc[i][j][r]);   // LDS ds_add_f32
    if (l16 == 0)
#pragma unroll
      for (int r = 0; r < 4; r++)
        atomicAdd(&redS[d0 + r], accs[i][r]);
  }
  __syncthreads();
  float* dst = KVp + ((size_t)ssplit * 64 + bh) * 4096;
  for (int i = tid; i < 4096; i += 256) dst[i] = red[i];
  if (tid < 64) Ksp[((size_t)ssplit * 64 + bh) * 64 + tid] = redS[tid];
}

// ---------------- attn[s][h*64+v] = (Q[s,:]@KV) / (Q[s,:]@Ksum + eps), bf16 out ----------------
__global__ __launch_bounds__(256) void attn_kernel(const u16* __restrict__ qbuf,
                                                   const float* __restrict__ KVp,
                                                   const float* __restrict__ Ksp,
                                                   u16* __restrict__ attn)
{
  __shared__ u16 KVt[64 * 72];   // [v][d], stride 72
  int tid = threadIdx.x;
  int bh = blockIdx.y;
  int b = bh >> 4, h = bh & 15;
  int s0 = blockIdx.x * 128;
  const float* kvsrc = KVp + (size_t)bh * 4096;
  for (int i = tid; i < 4096; i += 256) {
    float s = kvsrc[i] + kvsrc[i + 64*4096] + kvsrc[i + 2*64*4096] + kvsrc[i + 3*64*4096];
    int d = i >> 6, v = i & 63;
    KVt[v * 72 + d] = f2bf(s);
  }
  __syncthreads();
  int wave = tid >> 6, lane = tid & 63, quad = lane >> 4, l16 = lane & 15;

  const float* kssrc = Ksp + (size_t)bh * 64;
  short8 bks[2];
#pragma unroll
  for (int ks = 0; ks < 2; ++ks)
#pragma unroll
    for (int jj = 0; jj < 8; ++jj) {
      int d = ks*32 + quad*8 + jj;
      float s = kssrc[d] + kssrc[d + 64*64] + kssrc[d + 2*64*64] + kssrc[d + 3*64*64];
      bks[ks][jj] = (short)f2bf(s);
    }

  f32x4 acc[2][4], accn[2];
#pragma unroll
  for (int i = 0; i < 2; i++) {
    accn[i] = (f32x4)0.0f;
#pragma unroll
    for (int j = 0; j < 4; j++) acc[i][j] = (f32x4)0.0f;
  }

#pragma unroll
  for (int ks = 0; ks < 2; ++ks) {
    short8 bfr[4];
#pragma unroll
    for (int j = 0; j < 4; j++)
      bfr[j] = *(const short8*)(&KVt[(j*16 + l16) * 72 + ks*32 + quad*8]);
#pragma unroll
    for (int i = 0; i < 2; i++) {
      int row = s0 + wave * 32 + i * 16 + l16;
      short8 afr = *(const short8*)(qbuf + (size_t)(b * S_ + row) * D_ + h*HD_ + ks*32 + quad*8);
#pragma unroll
      for (int j = 0; j < 4; j++)
        acc[i][j] = __builtin_amdgcn_mfma_f32_16x16x32_bf16(afr, bfr[j], acc[i][j], 0, 0, 0);
      accn[i] = __builtin_amdgcn_mfma_f32_16x16x32_bf16(afr, bks[ks], accn[i], 0, 0, 0);
    }
  }
#pragma unroll
  for (int i = 0; i < 2; i++) {
    int rb = wave * 32 + i * 16 + quad * 4;
#pragma unroll
    for (int j = 0; j < 4; j++) {
      int col = h * HD_ + j * 16 + l16;
#pragma unroll
      for (int r = 0; r < 4; r++) {
        float o = acc[i][j][r] / (accn[i][r] + 1e-6f);
        attn[(size_t)(b * S_ + s0 + rb + r) * D_ + col] = f2bf(o);
      }
    }
  }
}

extern "C" void kernel_launch(void* const* d_in, const int* in_sizes, int n_in,
                              void* d_out, int out_size, void* d_ws, size_t ws_size,
                              hipStream_t stream) {
  const float* x    = (const float*)d_in[0];
  const float* Wqkv = (const float*)d_in[1];
  const float* Wo   = (const float*)d_in[2];
  float* out = (float*)d_out;
  char* ws = (char*)d_ws;
  if (ws_size < WS_NEEDED) return;  // visible failure, no corruption

  u16*   xb    = (u16*)  (ws + OFF_XB);
  u16*   wqkvt = (u16*)  (ws + OFF_WQKVT);
  u16*   wot   = (u16*)  (ws + OFF_WOT);
  u16*   qbuf  = (u16*)  (ws + OFF_QBUF);
  u16*   kt    = (u16*)  (ws + OFF_KT);
  u16*   vt    = (u16*)  (ws + OFF_VT);
  float* kvp   = (float*)(ws + OFF_KV);
  float* ksp   = (float*)(ws + OFF_KSUM);
  u16*   attnb = (u16*)  (ws + OFF_KT);    // aliases Kt: dead after kv_kernel

  prep_kernel<<<20480, 256, 0, stream>>>(x, xb, Wqkv, wqkvt, Wo, wot);
  // qkv = x @ Wqkv; epilogue splits Q (elu, [M][1024]) / Kt,Vt (transposed [bh][d][S])
  gemm256<<<dim3(N1_/256, M_/256), 512, 0, stream>>>(xb, wqkvt, nullptr, qbuf, kt, vt,
                                                     M_, N1_, D_, 1);
  kv_kernel<<<dim3(64, NSPLIT_), 256, 0, stream>>>(kt, vt, kvp, ksp);
  attn_kernel<<<dim3(32, 64), 256, 0, stream>>>(qbuf, kvp, ksp, attnb);
  // final = attn @ Wo, fp32 out
  gemm256<<<dim3(D_/256, M_/256), 512, 0, stream>>>(attnb, wot, out, nullptr, nullptr, nullptr,
                                                    M_, D_, D_, 0);
}